// Round 20
// baseline (98.590 us; speedup 1.0000x reference)
//
#include <hip/hip_runtime.h>

#define NNODES 2048
#define NHEAD 8
#define DKDIM 64

typedef unsigned int uint;
typedef unsigned short ushort;
typedef unsigned char uchar;
typedef __fp16 h2 __attribute__((ext_vector_type(2)));
typedef __fp16 h8 __attribute__((ext_vector_type(8)));
typedef float f16v __attribute__((ext_vector_type(16)));

#define KSCALE 0.18033688011112042f   // 0.125 * log2(e)
#define CLAMP2 14.426950408889634f    // 10 * log2(e)

__device__ __forceinline__ uint pk2(float a, float b) {
    union { h2 h; uint u; } x; x.h = __builtin_amdgcn_cvt_pkrtz(a, b); return x.u;
}

// ---- prep12: one kernel, three parts (identical to R17) ----
__global__ void prep12(const float* __restrict__ k, const float* __restrict__ v,
                       uint4* __restrict__ kc4, uint4* __restrict__ vt4,
                       uint4* __restrict__ A4) {
    __shared__ float tile[64][65];
    int b = blockIdx.x, t = threadIdx.x;
    if (b < 512) {
        int i = b * 256 + t;
        int f = i >> 6, l = i & 63;
        int jq = f & 3, sr = (f >> 2) & 1, ts = (f >> 3) & 31, h = f >> 8;
        int node = ts * 64 + sr * 32 + (l & 31);
        int dim0 = (2 * jq + (l >> 5)) * 8;
        const float* src = k + (size_t)node * 512 + h * 64 + dim0;
        float4 f0 = *(const float4*)src;
        float4 f1 = *(const float4*)(src + 4);
        uint4 o;
        o.x = pk2(f0.x * KSCALE, f0.y * KSCALE);
        o.y = pk2(f0.z * KSCALE, f0.w * KSCALE);
        o.z = pk2(f1.x * KSCALE, f1.y * KSCALE);
        o.w = pk2(f1.z * KSCALE, f1.w * KSCALE);
        kc4[(size_t)f * 64 + l] = o;
    } else if (b < 768) {
        int bv = b - 512;
        int h = bv & 7, tn = bv >> 3;
        int nl = t >> 2, dq = (t & 3) * 16;
        const float* src = v + (size_t)(tn * 64 + nl) * 512 + h * 64 + dq;
#pragma unroll
        for (int i = 0; i < 4; ++i) {
            float4 f = *(const float4*)(src + i * 4);
            tile[nl][dq + i * 4 + 0] = f.x;
            tile[nl][dq + i * 4 + 1] = f.y;
            tile[nl][dq + i * 4 + 2] = f.z;
            tile[nl][dq + i * 4 + 3] = f.w;
        }
        __syncthreads();
#pragma unroll
        for (int rep = 0; rep < 2; ++rep) {
            int slot = rep * 256 + t;
            int fsub = slot >> 6, l = slot & 63;
            int srv = fsub >> 2, ks = (fsub >> 1) & 1, dg = fsub & 1;
            int dim = dg * 32 + (l & 31);
            int s8 = (srv * 4 + ks * 2 + (l >> 5)) * 8;
            uint4 o;
            o.x = pk2(tile[s8 + 0][dim], tile[s8 + 1][dim]);
            o.y = pk2(tile[s8 + 2][dim], tile[s8 + 3][dim]);
            o.z = pk2(tile[s8 + 4][dim], tile[s8 + 5][dim]);
            o.w = pk2(tile[s8 + 6][dim], tile[s8 + 7][dim]);
            int fV = (h * 32 + tn) * 8 + srv * 4 + ks * 2 + dg;
            vt4[(size_t)fV * 64 + l] = o;
        }
    } else {
        uint4 zz = {0u, 0u, 0u, 0u};
        A4[(size_t)(b - 768) * 512 + t] = zz;
        A4[(size_t)(b - 768) * 512 + t + 256] = zz;
    }
}

// ---- histA: A[dst][src] 4-bit nibbles, packed atomics (4.5us, measured R18) ----
__global__ void histA(const int* __restrict__ es, const int* __restrict__ ed,
                      uint* __restrict__ A32, int E) {
    int i = blockIdx.x * 256 + threadIdx.x;
    if (i < E) {
        uint idx = (uint)ed[i] * 2048u + (uint)es[i];
        atomicAdd(&A32[idx >> 3], 1u << ((idx & 7) * 4));
    }
}

// ---- dense masked attention (byte-identical to R17, launch_bounds(512,2));
//      launched 3x this round: attn17 = (dur_us - 55.5) / 2 ----
__global__ void __launch_bounds__(512, 2) attn_kernel(
    const float* __restrict__ q, const char* __restrict__ kc, const char* __restrict__ vt,
    const uchar* __restrict__ A8, float* __restrict__ out) {
    __shared__ float CL[64 * 68];
    __shared__ float CLz[64];

    int b = blockIdx.x;
    int j = b & 7, idx = b >> 3;
    int dt = (j & 3) * 8 + (idx >> 2);
    int h = (j >> 2) * 4 + (idx & 3);
    int dst0 = dt * 64;
    int t = threadIdx.x;
    int w = t >> 6, half = w >> 2;
    int u = w & 3, sr = u >> 1, dc = u & 1;
    int l = t & 63, lm = l & 31, hi = l >> 5;

    int ts0 = half * 16;
    const char* kBase = kc + ((size_t)(h * 32 + ts0) * 8 + sr * 4) * 1024 + l * 16;
    const char* vBase = vt + ((size_t)(h * 32 + ts0) * 8 + sr * 4) * 1024 + l * 16;
    const char* aRow = (const char*)A8 + (size_t)(dst0 + dc * 32 + lm) * 1024 + sr * 16
                       + ts0 * 32;

    h8 qf[4];
    {
        const float* qp = q + (size_t)(dst0 + dc * 32 + lm) * 512 + h * 64 + hi * 8;
#pragma unroll
        for (int jq = 0; jq < 4; ++jq) {
            float4 f0 = *(const float4*)(qp + jq * 16);
            float4 f1 = *(const float4*)(qp + jq * 16 + 4);
            union { uint u4[4]; h8 v; } U;
            U.u4[0] = pk2(f0.x, f0.y); U.u4[1] = pk2(f0.z, f0.w);
            U.u4[2] = pk2(f1.x, f1.y); U.u4[3] = pk2(f1.z, f1.w);
            qf[jq] = U.v;
        }
    }

    f16v of[2];
#pragma unroll
    for (int dg = 0; dg < 2; ++dg)
#pragma unroll
        for (int i = 0; i < 16; ++i) of[dg][i] = 0.f;
    float z = 0.f;

    uint4 kcur[4], knxt[4], vcur[4];
    uint4 ac, an;

#pragma unroll
    for (int jq = 0; jq < 4; ++jq)
        kcur[jq] = *(const uint4*)(kBase + jq * 1024);
    ac = *(const uint4*)aRow;

    for (int it = 0; it < 16; ++it) {
        size_t toff = (size_t)it * 8192;
#pragma unroll
        for (int ks = 0; ks < 2; ++ks)
#pragma unroll
            for (int dg = 0; dg < 2; ++dg)
                vcur[ks * 2 + dg] = *(const uint4*)(vBase + toff + (ks * 2 + dg) * 1024);
        int itn = (it < 15) ? it + 1 : it;
        an = *(const uint4*)(aRow + itn * 32);

        f16v sacc;
#pragma unroll
        for (int i = 0; i < 16; ++i) sacc[i] = 0.f;
        __builtin_amdgcn_s_setprio(1);
#pragma unroll
        for (int jq = 0; jq < 4; ++jq) {
            union { uint4 u; h8 v; } KF; KF.u = kcur[jq];
            sacc = __builtin_amdgcn_mfma_f32_32x32x16_f16(KF.v, qf[jq], sacc, 0, 0, 0);
        }
        __builtin_amdgcn_s_setprio(0);

#pragma unroll
        for (int jq = 0; jq < 4; ++jq)
            knxt[jq] = *(const uint4*)(kBase + (size_t)itn * 8192 + jq * 1024);

        uint W[4][2];
        {
            const uint* aw4 = (const uint*)&ac;
#pragma unroll
            for (int G = 0; G < 4; ++G) {
                uint aw = aw4[G];
                float ee[4];
#pragma unroll
                for (int j2 = 0; j2 < 4; ++j2) {
                    float sc = fminf(fmaxf(sacc[4 * G + j2], -CLAMP2), CLAMP2);
                    ee[j2] = exp2f(sc) * (float)((aw >> (16 * hi + 4 * j2)) & 15u);
                    z += ee[j2];
                }
                W[G][0] = pk2(ee[0], ee[1]);
                W[G][1] = pk2(ee[2], ee[3]);
            }
        }
        uint Wx[4][2];
#pragma unroll
        for (int G = 0; G < 4; ++G) {
            Wx[G][0] = __shfl_xor(W[G][0], 32);
            Wx[G][1] = __shfl_xor(W[G][1], 32);
        }

        __builtin_amdgcn_s_setprio(1);
#pragma unroll
        for (int ks = 0; ks < 2; ++ks) {
            union { uint u4[4]; h8 v; } S;
            S.u4[0] = hi ? Wx[2 * ks + 1][0] : W[2 * ks][0];
            S.u4[1] = hi ? Wx[2 * ks + 1][1] : W[2 * ks][1];
            S.u4[2] = hi ? W[2 * ks + 1][0] : Wx[2 * ks][0];
            S.u4[3] = hi ? W[2 * ks + 1][1] : Wx[2 * ks][1];
#pragma unroll
            for (int dg = 0; dg < 2; ++dg) {
                union { uint4 u; h8 v; } VF; VF.u = vcur[ks * 2 + dg];
                of[dg] = __builtin_amdgcn_mfma_f32_32x32x16_f16(VF.v, S.v, of[dg], 0, 0, 0);
            }
        }
        __builtin_amdgcn_s_setprio(0);

#pragma unroll
        for (int jq = 0; jq < 4; ++jq) kcur[jq] = knxt[jq];
        ac = an;
    }

    z += __shfl_xor(z, 32);

    int gid = half * 2 + sr;
    for (int p = 0; p < 4; ++p) {
        if (gid == p) {
#pragma unroll
            for (int dg = 0; dg < 2; ++dg)
#pragma unroll
                for (int reg = 0; reg < 16; ++reg) {
                    int dim = dg * 32 + (reg & 3) + 8 * (reg >> 2) + 4 * hi;
                    int idx2 = (dc * 32 + lm) * 68 + dim;
                    if (p == 0) CL[idx2] = of[dg][reg];
                    else CL[idx2] += of[dg][reg];
                }
            if (hi == 0) {
                if (p == 0) CLz[dc * 32 + lm] = z;
                else CLz[dc * 32 + lm] += z;
            }
        }
        __syncthreads();
    }

    {
        int dst = t >> 3, d8 = t & 7;
        float inv = 1.0f / CLz[dst];
        float4 o0 = *(float4*)(CL + dst * 68 + d8 * 8);
        float4 o1 = *(float4*)(CL + dst * 68 + d8 * 8 + 4);
        o0.x *= inv; o0.y *= inv; o0.z *= inv; o0.w *= inv;
        o1.x *= inv; o1.y *= inv; o1.z *= inv; o1.w *= inv;
        float* op = out + (size_t)(dst0 + dst) * 512 + h * 64 + d8 * 8;
        *(float4*)op = o0;
        *(float4*)(op + 4) = o1;
    }
}

// ---------------- launch ----------------

extern "C" void kernel_launch(void* const* d_in, const int* in_sizes, int n_in,
                              void* d_out, int out_size, void* d_ws, size_t ws_size,
                              hipStream_t stream) {
    const float* q = (const float*)d_in[0];
    const float* k = (const float*)d_in[1];
    const float* v = (const float*)d_in[2];
    const int* esrc = (const int*)d_in[3];
    const int* edst = (const int*)d_in[4];
    float* out = (float*)d_out;
    const int E = in_sizes[3];

    uchar* A8 = (uchar*)d_ws;                                  // 2MB  A[dst][src] 4-bit
    char* kc = (char*)(A8 + (size_t)NNODES * NNODES / 2);      // 2MB  fp16 frag-major K
    char* vt = kc + (size_t)NHEAD * NNODES * DKDIM * 2;        // 2MB  fp16 frag-major V^T

    prep12<<<1024, 256, 0, stream>>>(k, v, (uint4*)kc, (uint4*)vt, (uint4*)A8);
    histA<<<(E + 255) / 256, 256, 0, stream>>>(esrc, edst, (uint*)A8, E);
    // measurement: attn 3x (pure function, idempotent).
    // attn17 = (dur_us - 55.5) / 2.
    attn_kernel<<<256, 512, 0, stream>>>(q, kc, vt, A8, out);
    attn_kernel<<<256, 512, 0, stream>>>(q, kc, vt, A8, out);
    attn_kernel<<<256, 512, 0, stream>>>(q, kc, vt, A8, out);
}

// Round 21
// 55.391 us; speedup vs baseline: 1.7799x; 1.7799x over previous
//
#include <hip/hip_runtime.h>

#define NNODES 2048
#define NHEAD 8
#define DKDIM 64

typedef unsigned int uint;
typedef unsigned short ushort;
typedef unsigned char uchar;
typedef __fp16 h2 __attribute__((ext_vector_type(2)));
typedef __fp16 h8 __attribute__((ext_vector_type(8)));
typedef float f16v __attribute__((ext_vector_type(16)));

#define KSCALE 0.18033688011112042f   // 0.125 * log2(e)
#define CLAMP2 14.426950408889634f    // 10 * log2(e)

__device__ __forceinline__ uint pk2(float a, float b) {
    union { h2 h; uint u; } x; x.h = __builtin_amdgcn_cvt_pkrtz(a, b); return x.u;
}

// ---- prep12: one kernel, three parts (identical to R17) ----
__global__ void prep12(const float* __restrict__ k, const float* __restrict__ v,
                       uint4* __restrict__ kc4, uint4* __restrict__ vt4,
                       uint4* __restrict__ A4) {
    __shared__ float tile[64][65];
    int b = blockIdx.x, t = threadIdx.x;
    if (b < 512) {
        int i = b * 256 + t;
        int f = i >> 6, l = i & 63;
        int jq = f & 3, sr = (f >> 2) & 1, ts = (f >> 3) & 31, h = f >> 8;
        int node = ts * 64 + sr * 32 + (l & 31);
        int dim0 = (2 * jq + (l >> 5)) * 8;
        const float* src = k + (size_t)node * 512 + h * 64 + dim0;
        float4 f0 = *(const float4*)src;
        float4 f1 = *(const float4*)(src + 4);
        uint4 o;
        o.x = pk2(f0.x * KSCALE, f0.y * KSCALE);
        o.y = pk2(f0.z * KSCALE, f0.w * KSCALE);
        o.z = pk2(f1.x * KSCALE, f1.y * KSCALE);
        o.w = pk2(f1.z * KSCALE, f1.w * KSCALE);
        kc4[(size_t)f * 64 + l] = o;
    } else if (b < 768) {
        int bv = b - 512;
        int h = bv & 7, tn = bv >> 3;
        int nl = t >> 2, dq = (t & 3) * 16;
        const float* src = v + (size_t)(tn * 64 + nl) * 512 + h * 64 + dq;
#pragma unroll
        for (int i = 0; i < 4; ++i) {
            float4 f = *(const float4*)(src + i * 4);
            tile[nl][dq + i * 4 + 0] = f.x;
            tile[nl][dq + i * 4 + 1] = f.y;
            tile[nl][dq + i * 4 + 2] = f.z;
            tile[nl][dq + i * 4 + 3] = f.w;
        }
        __syncthreads();
#pragma unroll
        for (int rep = 0; rep < 2; ++rep) {
            int slot = rep * 256 + t;
            int fsub = slot >> 6, l = slot & 63;
            int srv = fsub >> 2, ks = (fsub >> 1) & 1, dg = fsub & 1;
            int dim = dg * 32 + (l & 31);
            int s8 = (srv * 4 + ks * 2 + (l >> 5)) * 8;
            uint4 o;
            o.x = pk2(tile[s8 + 0][dim], tile[s8 + 1][dim]);
            o.y = pk2(tile[s8 + 2][dim], tile[s8 + 3][dim]);
            o.z = pk2(tile[s8 + 4][dim], tile[s8 + 5][dim]);
            o.w = pk2(tile[s8 + 6][dim], tile[s8 + 7][dim]);
            int fV = (h * 32 + tn) * 8 + srv * 4 + ks * 2 + dg;
            vt4[(size_t)fV * 64 + l] = o;
        }
    } else {
        uint4 zz = {0u, 0u, 0u, 0u};
        A4[(size_t)(b - 768) * 512 + t] = zz;
        A4[(size_t)(b - 768) * 512 + t + 256] = zz;
    }
}

// ---- histA: A_perm[dt][ts][sr][dc][lm] uint4 nibble layout — wave-order
//      coalesced (one contiguous 512B segment per wave-load). nib = s&7,
//      word G = (s>>3)&3: extraction in-kernel is bit-identical to before. ----
__global__ void histA(const int* __restrict__ es, const int* __restrict__ ed,
                      uint* __restrict__ A32, int E) {
    int i = blockIdx.x * 256 + threadIdx.x;
    if (i < E) {
        uint s = (uint)es[i], d = (uint)ed[i];
        uint uidx = ((d >> 6) << 14) + ((s >> 6) << 9) + (((s >> 5) & 1u) << 8) +
                    (((d >> 5) & 1u) << 7) + ((d & 31u) << 2) + ((s >> 3) & 3u);
        atomicAdd(&A32[uidx], 1u << ((s & 7u) << 2));
    }
}

// ---- dense masked attention: barrier-free, frag-major K/V, 2-deep pipeline ----
// R21: manual 2-tile software pipeline (disjoint reg sets per tile) to fill
// the serial chain {loads -> QK -> exp -> shfl -> PV} with independent work;
// A-mask loads now contiguous (permuted layout). ~190 VGPR peak < 256 (512,2).
__global__ void __launch_bounds__(512, 2) attn_kernel(
    const float* __restrict__ q, const char* __restrict__ kc, const char* __restrict__ vt,
    const uchar* __restrict__ A8, float* __restrict__ out) {
    __shared__ float CL[64 * 68];
    __shared__ float CLz[64];

    int b = blockIdx.x;
    int j = b & 7, idx = b >> 3;
    int dt = (j & 3) * 8 + (idx >> 2);
    int h = (j >> 2) * 4 + (idx & 3);
    int dst0 = dt * 64;
    int t = threadIdx.x;
    int w = t >> 6, half = w >> 2;
    int u = w & 3, sr = u >> 1, dc = u & 1;
    int l = t & 63, lm = l & 31, hi = l >> 5;

    int ts0 = half * 16;
    const char* kBase = kc + ((size_t)(h * 32 + ts0) * 8 + sr * 4) * 1024 + l * 16;
    const char* vBase = vt + ((size_t)(h * 32 + ts0) * 8 + sr * 4) * 1024 + l * 16;
    // permuted A: dt*65536 + ts*2048 + sr*1024 + dc*512 + lm*16
    const char* aRow = (const char*)A8 + (size_t)dt * 65536 + (size_t)ts0 * 2048 +
                       sr * 1024 + dc * 512 + lm * 16;

    h8 qf[4];
    {
        const float* qp = q + (size_t)(dst0 + dc * 32 + lm) * 512 + h * 64 + hi * 8;
#pragma unroll
        for (int jq = 0; jq < 4; ++jq) {
            float4 f0 = *(const float4*)(qp + jq * 16);
            float4 f1 = *(const float4*)(qp + jq * 16 + 4);
            union { uint u4[4]; h8 v; } U;
            U.u4[0] = pk2(f0.x, f0.y); U.u4[1] = pk2(f0.z, f0.w);
            U.u4[2] = pk2(f1.x, f1.y); U.u4[3] = pk2(f1.z, f1.w);
            qf[jq] = U.v;
        }
    }

    f16v of[2];
#pragma unroll
    for (int dg = 0; dg < 2; ++dg)
#pragma unroll
        for (int i = 0; i < 16; ++i) of[dg][i] = 0.f;
    float z = 0.f;

    uint4 k0f[4], k1f[4], v0f[4], v1f[4];
    uint4 ac0, ac1;

    // prologue: K frags + A words for tiles 0,1 of this wave's range
#pragma unroll
    for (int f = 0; f < 4; ++f) {
        k0f[f] = *(const uint4*)(kBase + f * 1024);
        k1f[f] = *(const uint4*)(kBase + 8192 + f * 1024);
    }
    ac0 = *(const uint4*)aRow;
    ac1 = *(const uint4*)(aRow + 2048);

    for (int p = 0; p < 8; ++p) {
        int r0t = 2 * p, r1t = 2 * p + 1;
        size_t o0 = (size_t)r0t * 8192, o1 = (size_t)r1t * 8192;
        // V loads for both tiles (consumed at PV, ~400+ cyc later)
#pragma unroll
        for (int f = 0; f < 4; ++f) {
            v0f[f] = *(const uint4*)(vBase + o0 + f * 1024);
            v1f[f] = *(const uint4*)(vBase + o1 + f * 1024);
        }

        // QK both tiles (independent MFMA chains)
        f16v sacc0, sacc1;
#pragma unroll
        for (int i = 0; i < 16; ++i) { sacc0[i] = 0.f; sacc1[i] = 0.f; }
        __builtin_amdgcn_s_setprio(1);
#pragma unroll
        for (int jq = 0; jq < 4; ++jq) {
            union { uint4 u; h8 v; } KF; KF.u = k0f[jq];
            sacc0 = __builtin_amdgcn_mfma_f32_32x32x16_f16(KF.v, qf[jq], sacc0, 0, 0, 0);
        }
#pragma unroll
        for (int jq = 0; jq < 4; ++jq) {
            union { uint4 u; h8 v; } KF; KF.u = k1f[jq];
            sacc1 = __builtin_amdgcn_mfma_f32_32x32x16_f16(KF.v, qf[jq], sacc1, 0, 0, 0);
        }
        __builtin_amdgcn_s_setprio(0);

        // K prefetch for tiles +2 (regs dead after QK issue)
        int n0 = (p < 7) ? r0t + 2 : r0t;
        int n1 = (p < 7) ? r1t + 2 : r1t;
#pragma unroll
        for (int f = 0; f < 4; ++f) {
            k0f[f] = *(const uint4*)(kBase + (size_t)n0 * 8192 + f * 1024);
            k1f[f] = *(const uint4*)(kBase + (size_t)n1 * 8192 + f * 1024);
        }

        // exp + mask + z for both tiles
        uint W0[4][2], W1[4][2];
        {
            const uint* a0 = (const uint*)&ac0;
            const uint* a1 = (const uint*)&ac1;
#pragma unroll
            for (int G = 0; G < 4; ++G) {
                float e0[4], e1[4];
#pragma unroll
                for (int j2 = 0; j2 < 4; ++j2) {
                    float s0 = fminf(fmaxf(sacc0[4 * G + j2], -CLAMP2), CLAMP2);
                    float s1 = fminf(fmaxf(sacc1[4 * G + j2], -CLAMP2), CLAMP2);
                    e0[j2] = exp2f(s0) * (float)((a0[G] >> (16 * hi + 4 * j2)) & 15u);
                    e1[j2] = exp2f(s1) * (float)((a1[G] >> (16 * hi + 4 * j2)) & 15u);
                    z += e0[j2] + e1[j2];
                }
                W0[G][0] = pk2(e0[0], e0[1]); W0[G][1] = pk2(e0[2], e0[3]);
                W1[G][0] = pk2(e1[0], e1[1]); W1[G][1] = pk2(e1[2], e1[3]);
            }
        }

        // A prefetch for tiles +2
        ac0 = *(const uint4*)(aRow + (size_t)n0 * 2048);
        ac1 = *(const uint4*)(aRow + (size_t)n1 * 2048);

        // cross-half exchange both tiles (independent shfl batches)
        uint Wx0[4][2], Wx1[4][2];
#pragma unroll
        for (int G = 0; G < 4; ++G) {
            Wx0[G][0] = __shfl_xor(W0[G][0], 32);
            Wx0[G][1] = __shfl_xor(W0[G][1], 32);
            Wx1[G][0] = __shfl_xor(W1[G][0], 32);
            Wx1[G][1] = __shfl_xor(W1[G][1], 32);
        }

        // PV both tiles
        __builtin_amdgcn_s_setprio(1);
#pragma unroll
        for (int ks = 0; ks < 2; ++ks) {
            union { uint u4[4]; h8 v; } S0, S1;
            S0.u4[0] = hi ? Wx0[2 * ks + 1][0] : W0[2 * ks][0];
            S0.u4[1] = hi ? Wx0[2 * ks + 1][1] : W0[2 * ks][1];
            S0.u4[2] = hi ? W0[2 * ks + 1][0] : Wx0[2 * ks][0];
            S0.u4[3] = hi ? W0[2 * ks + 1][1] : Wx0[2 * ks][1];
            S1.u4[0] = hi ? Wx1[2 * ks + 1][0] : W1[2 * ks][0];
            S1.u4[1] = hi ? Wx1[2 * ks + 1][1] : W1[2 * ks][1];
            S1.u4[2] = hi ? W1[2 * ks + 1][0] : Wx1[2 * ks][0];
            S1.u4[3] = hi ? W1[2 * ks + 1][1] : Wx1[2 * ks][1];
#pragma unroll
            for (int dg = 0; dg < 2; ++dg) {
                union { uint4 u; h8 v; } VF0, VF1;
                VF0.u = v0f[ks * 2 + dg];
                VF1.u = v1f[ks * 2 + dg];
                of[dg] = __builtin_amdgcn_mfma_f32_32x32x16_f16(VF0.v, S0.v, of[dg], 0, 0, 0);
                of[dg] = __builtin_amdgcn_mfma_f32_32x32x16_f16(VF1.v, S1.v, of[dg], 0, 0, 0);
            }
        }
        __builtin_amdgcn_s_setprio(0);
    }

    z += __shfl_xor(z, 32);

    int gid = half * 2 + sr;
    for (int p = 0; p < 4; ++p) {
        if (gid == p) {
#pragma unroll
            for (int dg = 0; dg < 2; ++dg)
#pragma unroll
                for (int reg = 0; reg < 16; ++reg) {
                    int dim = dg * 32 + (reg & 3) + 8 * (reg >> 2) + 4 * hi;
                    int idx2 = (dc * 32 + lm) * 68 + dim;
                    if (p == 0) CL[idx2] = of[dg][reg];
                    else CL[idx2] += of[dg][reg];
                }
            if (hi == 0) {
                if (p == 0) CLz[dc * 32 + lm] = z;
                else CLz[dc * 32 + lm] += z;
            }
        }
        __syncthreads();
    }

    {
        int dst = t >> 3, d8 = t & 7;
        float inv = 1.0f / CLz[dst];
        float4 o0 = *(float4*)(CL + dst * 68 + d8 * 8);
        float4 o1 = *(float4*)(CL + dst * 68 + d8 * 8 + 4);
        o0.x *= inv; o0.y *= inv; o0.z *= inv; o0.w *= inv;
        o1.x *= inv; o1.y *= inv; o1.z *= inv; o1.w *= inv;
        float* op = out + (size_t)(dst0 + dst) * 512 + h * 64 + d8 * 8;
        *(float4*)op = o0;
        *(float4*)(op + 4) = o1;
    }
}

// ---------------- launch ----------------

extern "C" void kernel_launch(void* const* d_in, const int* in_sizes, int n_in,
                              void* d_out, int out_size, void* d_ws, size_t ws_size,
                              hipStream_t stream) {
    const float* q = (const float*)d_in[0];
    const float* k = (const float*)d_in[1];
    const float* v = (const float*)d_in[2];
    const int* esrc = (const int*)d_in[3];
    const int* edst = (const int*)d_in[4];
    float* out = (float*)d_out;
    const int E = in_sizes[3];

    uchar* A8 = (uchar*)d_ws;                                  // 2MB  A_perm 4-bit
    char* kc = (char*)(A8 + (size_t)NNODES * NNODES / 2);      // 2MB  fp16 frag-major K
    char* vt = kc + (size_t)NHEAD * NNODES * DKDIM * 2;        // 2MB  fp16 frag-major V^T

    prep12<<<1024, 256, 0, stream>>>(k, v, (uint4*)kc, (uint4*)vt, (uint4*)A8);
    histA<<<(E + 255) / 256, 256, 0, stream>>>(esrc, edst, (uint*)A8, E);
    attn_kernel<<<256, 512, 0, stream>>>(q, kc, vt, A8, out);
}